// Round 1
// baseline (1405.937 us; speedup 1.0000x reference)
//
#include <hip/hip_runtime.h>
#include <stdint.h>

#define MDIM 4096
#define NDIM 4096
#define KDIM 4096
#define BATCH 4

typedef __bf16 bf16x8 __attribute__((ext_vector_type(8)));
typedef float f32x4 __attribute__((ext_vector_type(4)));

typedef const __attribute__((address_space(1))) void gvoid;
typedef __attribute__((address_space(3))) void lvoid;

// shared block scale: 2^(floor(log2(amax)) - 2), bit-exact exponent extract.
__device__ __forceinline__ void quant_scales(float amax, float& scale, float& inv_scale) {
    int ex = (int)(__float_as_uint(amax) >> 23) - 127;   // floor(log2(amax)) for normal amax
    ex = ex < -120 ? -120 : (ex > 120 ? 120 : ex);       // amax==0 -> q==0 anyway
    scale     = __int_as_float((ex + 125) << 23);        // 2^(ex-2)
    inv_scale = __int_as_float((129 - ex) << 23);        // 2^(2-ex)
}

// E2M1 fake-quant of one element; returns bf16 bits (exact: <=2 significant bits)
__device__ __forceinline__ ushort quant_one(float x, float scale, float inv_scale) {
    float a = fminf(fabsf(x) * inv_scale, 6.0f);
    float rstep = (a < 2.0f) ? 2.0f : ((a < 4.0f) ? 1.0f : 0.5f);
    float step  = (a < 2.0f) ? 0.5f : ((a < 4.0f) ? 1.0f : 2.0f);
    float q = rintf(a * rstep) * step;                   // RNE == jnp.round
    float v = copysignf(q * scale, x);
    return (ushort)(__float_as_uint(v) >> 16);           // exact fp32->bf16
}

// A: (b, m, k) fp32, quantize along k (contiguous). 8 elem/thread; 4 threads = one 32-block.
__global__ __launch_bounds__(256) void quant_a_kernel(const float* __restrict__ A,
                                                      ushort* __restrict__ Aq) {
    const long long base = ((long long)blockIdx.x * 256 + threadIdx.x) * 8;
    const float4 v0 = *(const float4*)(A + base);
    const float4 v1 = *(const float4*)(A + base + 4);
    float x[8] = {v0.x, v0.y, v0.z, v0.w, v1.x, v1.y, v1.z, v1.w};
    float amax = 0.0f;
#pragma unroll
    for (int i = 0; i < 8; ++i) amax = fmaxf(amax, fabsf(x[i]));
    // reduce over the aligned 4-lane group that owns this 32-block
    amax = fmaxf(amax, __shfl_xor(amax, 1));
    amax = fmaxf(amax, __shfl_xor(amax, 2));
    float scale, inv_scale;
    quant_scales(amax, scale, inv_scale);
    ushort o[8];
#pragma unroll
    for (int i = 0; i < 8; ++i) o[i] = quant_one(x[i], scale, inv_scale);
    uint4 pack;
    pack.x = (uint)o[0] | ((uint)o[1] << 16);
    pack.y = (uint)o[2] | ((uint)o[3] << 16);
    pack.z = (uint)o[4] | ((uint)o[5] << 16);
    pack.w = (uint)o[6] | ((uint)o[7] << 16);
    *(uint4*)(Aq + base) = pack;
}

// B: (b, k, n) fp32, quantize along k (stride N). Each thread owns one 32-block of one
// column n. Output written TRANSPOSED as Bqt (b, n, k) via LDS so GEMM gets k-contiguous
// operand with coalesced 256B row segments.
__global__ __launch_bounds__(256) void quant_b_kernel(const float* __restrict__ B,
                                                      ushort* __restrict__ Bqt) {
    __shared__ ushort S[64][132];   // [n][k], +4 pad: 66-dword row stride -> 2-way (free)
    const int b    = blockIdx.z;
    const int n0   = blockIdx.x * 64;
    const int k0   = blockIdx.y * 128;
    const int lane = threadIdx.x & 63;   // n within tile
    const int w    = threadIdx.x >> 6;   // which 32-k-block of the 128
    const float* src = B + ((long long)b * KDIM + (k0 + w * 32)) * NDIM + (n0 + lane);
    float x[32];
    float amax = 0.0f;
#pragma unroll
    for (int i = 0; i < 32; ++i) {
        x[i] = src[(size_t)i * NDIM];                    // coalesced 256B across wave
        amax = fmaxf(amax, fabsf(x[i]));
    }
    float scale, inv_scale;
    quant_scales(amax, scale, inv_scale);
#pragma unroll
    for (int i = 0; i < 32; ++i) S[lane][w * 32 + i] = quant_one(x[i], scale, inv_scale);
    __syncthreads();
    ushort* dstbase = Bqt + ((long long)b * NDIM + n0) * KDIM + k0;
#pragma unroll
    for (int it = 0; it < 4; ++it) {
        int G = it * 256 + threadIdx.x;   // 1024 granules of 16B: 64 rows x 16
        int row = G >> 4;
        int c = (G & 15) * 8;
        uint2 lo = *(const uint2*)&S[row][c];
        uint2 hi = *(const uint2*)&S[row][c + 4];
        uint4 out; out.x = lo.x; out.y = lo.y; out.z = hi.x; out.w = hi.y;
        *(uint4*)(dstbase + (size_t)row * KDIM + c) = out;   // 256B segments per row
    }
}

// C[b] = Aq[b] (M,K) @ Bqt[b]^T  (Bqt is (N,K)) — m97 structure: 128x128 tile, BK=32,
// 4 waves x 4x4 16x16x32 bf16 MFMA, global_load_lds width 16, ds_read_b128 fragments.
__global__ __launch_bounds__(256) void gemm_kernel(const ushort* __restrict__ Aq,
                                                   const ushort* __restrict__ Bqt,
                                                   float* __restrict__ C) {
    __shared__ __align__(16) ushort As[128 * 32];  // [m][k] row-major, 8KB
    __shared__ __align__(16) ushort Bs[128 * 32];  // [n][k] row-major, 8KB
    const int t = threadIdx.x;
    const int wave = t >> 6, lane = t & 63;
    const int wm = wave >> 1, wn = wave & 1;       // 2x2 waves of 64x64
    const int m0 = blockIdx.y * 128, n0 = blockIdx.x * 128;
    const int bb = blockIdx.z;

    const ushort* Abase = Aq  + (size_t)bb * MDIM * KDIM + (size_t)m0 * KDIM;
    const ushort* Bbase = Bqt + (size_t)bb * NDIM * KDIM + (size_t)n0 * KDIM;

    // staging granules: 512 x 16B per tile; wave w owns LDS bytes [w*2048, w*2048+2048)
    // so HW dest (wave-uniform base + lane*16) matches exactly.
    const int G0 = wave * 128 + lane;
    const int G1 = G0 + 64;
    const int r0 = G0 >> 2, c0 = (G0 & 3) * 8;
    const int r1 = G1 >> 2, c1 = (G1 & 3) * 8;

    const ushort* ga0 = Abase + (size_t)r0 * KDIM + c0;
    const ushort* ga1 = Abase + (size_t)r1 * KDIM + c1;
    const ushort* gb0 = Bbase + (size_t)r0 * KDIM + c0;
    const ushort* gb1 = Bbase + (size_t)r1 * KDIM + c1;

    f32x4 zero = {0.f, 0.f, 0.f, 0.f};
    f32x4 acc[4][4];
#pragma unroll
    for (int i = 0; i < 4; ++i)
#pragma unroll
        for (int j = 0; j < 4; ++j) acc[i][j] = zero;

    // fragment read offsets: A[m=lane&15][k=(lane>>4)*8+j], same for B^T
    const int aoff = (wm * 64 + (lane & 15)) * 32 + (lane >> 4) * 8;
    const int boff = (wn * 64 + (lane & 15)) * 32 + (lane >> 4) * 8;

    for (int kt = 0; kt < KDIM / 32; ++kt) {
        __builtin_amdgcn_global_load_lds((gvoid*)ga0, (lvoid*)((char*)As + G0 * 16), 16, 0, 0);
        __builtin_amdgcn_global_load_lds((gvoid*)ga1, (lvoid*)((char*)As + G1 * 16), 16, 0, 0);
        __builtin_amdgcn_global_load_lds((gvoid*)gb0, (lvoid*)((char*)Bs + G0 * 16), 16, 0, 0);
        __builtin_amdgcn_global_load_lds((gvoid*)gb1, (lvoid*)((char*)Bs + G1 * 16), 16, 0, 0);
        ga0 += 32; ga1 += 32; gb0 += 32; gb1 += 32;
        __syncthreads();

        bf16x8 af[4], bfr[4];
#pragma unroll
        for (int i = 0; i < 4; ++i) af[i]  = *(const bf16x8*)(As + aoff + i * 16 * 32);
#pragma unroll
        for (int i = 0; i < 4; ++i) bfr[i] = *(const bf16x8*)(Bs + boff + i * 16 * 32);
#pragma unroll
        for (int tm = 0; tm < 4; ++tm)
#pragma unroll
            for (int tn = 0; tn < 4; ++tn)
                acc[tm][tn] = __builtin_amdgcn_mfma_f32_16x16x32_bf16(af[tm], bfr[tn],
                                                                      acc[tm][tn], 0, 0, 0);
        __syncthreads();
    }

    // C/D layout: col = lane&15, row = (lane>>4)*4 + reg
    float* Cbase = C + ((size_t)bb * MDIM + m0) * NDIM + n0;
#pragma unroll
    for (int tm = 0; tm < 4; ++tm) {
        int row = wm * 64 + tm * 16 + ((lane >> 4) * 4);
#pragma unroll
        for (int tn = 0; tn < 4; ++tn) {
            int col = wn * 64 + tn * 16 + (lane & 15);
#pragma unroll
            for (int r = 0; r < 4; ++r)
                Cbase[(size_t)(row + r) * NDIM + col] = acc[tm][tn][r];
        }
    }
}

extern "C" void kernel_launch(void* const* d_in, const int* in_sizes, int n_in,
                              void* d_out, int out_size, void* d_ws, size_t ws_size,
                              hipStream_t stream) {
    (void)in_sizes; (void)n_in; (void)out_size; (void)ws_size;
    const float* A = (const float*)d_in[0];
    const float* B = (const float*)d_in[1];
    float* C = (float*)d_out;
    ushort* Aq  = (ushort*)d_ws;                               // 128 MiB
    ushort* Bqt = Aq + (size_t)BATCH * MDIM * KDIM;            // 128 MiB

    quant_a_kernel<<<(BATCH * (size_t)MDIM * KDIM) / 2048, 256, 0, stream>>>(A, Aq);
    dim3 gb(NDIM / 64, KDIM / 128, BATCH);
    quant_b_kernel<<<gb, 256, 0, stream>>>(B, Bqt);
    dim3 gg(NDIM / 128, MDIM / 128, BATCH);
    gemm_kernel<<<gg, 256, 0, stream>>>(Aq, Bqt, C);
}